// Round 13
// baseline (414.838 us; speedup 1.0000x reference)
//
#include <hip/hip_runtime.h>
#include <math.h>

#define NGRAPH 64
#define EPS_BN 1e-5f
#define AGG_BLOCKS 2048

typedef unsigned int uint32;
typedef unsigned short ushort16;
typedef __attribute__((ext_vector_type(8))) short short8v;
typedef __attribute__((ext_vector_type(4))) float float4v;

__device__ __forceinline__ float bf2f(uint32 u16) {
    return __uint_as_float(u16 << 16);
}
__device__ __forceinline__ ushort16 f2bf(float f) {
    uint32 u = __float_as_uint(f);
    return (ushort16)((u + 0x7fffu + ((u >> 16) & 1u)) >> 16);  // RNE
}
__device__ __forceinline__ uint32 pack2(float lo, float hi) {
    return (uint32)f2bf(lo) | ((uint32)f2bf(hi) << 16);
}

// ---------------- merged W prep + cnt zeroing ----------------
__global__ __launch_bounds__(256) void k_wprep_all(const float* __restrict__ W1,
                                                   const float* __restrict__ W2,
                                                   const float* __restrict__ W3,
                                                   ushort16* __restrict__ wt1,
                                                   ushort16* __restrict__ wt2,
                                                   ushort16* __restrict__ wt3,
                                                   int* __restrict__ cnt, int n) {
    int i = blockIdx.x * 256 + threadIdx.x;
    if (i < 16384) {
        int c = i >> 7, k = i & 127;
        wt1[i] = f2bf(W1[k * 128 + c]);
    } else if (i < 32768) {
        int j = i - 16384;
        int c = j >> 7, k = j & 127;
        wt2[j] = f2bf(W2[k * 128 + c]);
    } else if (i < 36864) {
        int j = i - 32768;
        int c = j >> 7, k = j & 127;  // c in [0,32)
        wt3[j] = f2bf(W3[k * 32 + c]);
    }
    if (i < n) cnt[i] = 0;
}

// ---------------- FUSED: layer-1 GEMM (no BN, no dinv scale) + edge histogram+rank ----------------
#define EB 256
__global__ __launch_bounds__(256) void k_gemm1_cnt(const float* __restrict__ A,
                                                   const ushort16* __restrict__ Wt,
                                                   ushort16* __restrict__ C, int nrows,
                                                   const int* __restrict__ dst,
                                                   int* __restrict__ cnt,
                                                   int* __restrict__ rank,
                                                   int ne, int epb) {
    constexpr int K = 128;
    constexpr int COLS = 128;
    constexpr int LDK = K + 8;
    __shared__ ushort16 As[64 * LDK];
    __shared__ ushort16 Bs[COLS * LDK];
    const int tid = threadIdx.x;
    const int bid = blockIdx.x;
    const int q = bid >> 2, r = bid & 3;

    if (r == 3 && q < EB) {
        const int beg = q * epb;
        const int end = min(beg + epb, ne);
        int e = beg + tid;
        for (; e + 3 * 256 < end; e += 4 * 256) {
            int d0 = dst[e], d1 = dst[e + 256], d2 = dst[e + 512], d3 = dst[e + 768];
            int r0 = atomicAdd(&cnt[d0], 1);
            int r1 = atomicAdd(&cnt[d1], 1);
            int r2 = atomicAdd(&cnt[d2], 1);
            int r3 = atomicAdd(&cnt[d3], 1);
            rank[e] = r0; rank[e + 256] = r1; rank[e + 512] = r2; rank[e + 768] = r3;
        }
        for (; e < end; e += 256) rank[e] = atomicAdd(&cnt[dst[e]], 1);
        return;
    }
    const int gidx = (q < EB) ? (3 * q + r) : (bid - EB);

    {
        const uint4* wg = (const uint4*)Wt;
        for (int i = tid; i < COLS * (K / 8); i += 256) {
            int rr = i >> 4, c8 = i & 15;
            *(uint4*)&Bs[rr * LDK + c8 * 8] = wg[i];
        }
    }
    const int w = tid >> 6;
    const int l = tid & 63;
    const int lr = l & 15;
    const int lg = l >> 4;
    constexpr int CT = COLS / 16;

    #pragma unroll
    for (int half = 0; half < 2; ++half) {
        const int row0 = gidx * 128 + half * 64;
        if (half) __syncthreads();
        const float* Af = A;
        for (int i = tid; i < 64 * (K / 4); i += 256) {
            int rr = i >> 5, c4 = i & 31;
            float4 a;
            if (row0 + rr < nrows) a = *(const float4*)&Af[(size_t)(row0 + rr) * K + c4 * 4];
            else a = make_float4(0.f, 0.f, 0.f, 0.f);
            ushort4 o;
            o.x = f2bf(a.x); o.y = f2bf(a.y); o.z = f2bf(a.z); o.w = f2bf(a.w);
            *(ushort4*)&As[rr * LDK + c4 * 4] = o;
        }
        __syncthreads();

        float4v acc[CT] = {};
        short8v afrag[4];
        #pragma unroll
        for (int kk = 0; kk < 4; ++kk)
            afrag[kk] = *(const short8v*)&As[(w * 16 + lr) * LDK + kk * 32 + lg * 8];
        #pragma unroll
        for (int kk = 0; kk < 4; ++kk) {
            #pragma unroll
            for (int ct = 0; ct < CT; ++ct) {
                short8v b = *(const short8v*)&Bs[(ct * 16 + lr) * LDK + kk * 32 + lg * 8];
                acc[ct] = __builtin_amdgcn_mfma_f32_16x16x32_bf16(afrag[kk], b, acc[ct], 0, 0, 0);
            }
        }
        #pragma unroll
        for (int rr = 0; rr < 4; ++rr) {
            int gr = row0 + w * 16 + lg * 4 + rr;
            if (gr < nrows) {
                #pragma unroll
                for (int ct = 0; ct < CT; ++ct)
                    C[(size_t)gr * COLS + ct * 16 + lr] = f2bf(acc[ct][rr]);
            }
        }
    }
}

// ---------------- hierarchical exclusive scan ----------------
__global__ __launch_bounds__(1024) void k_scan1(const int* __restrict__ cnt,
                                                int* __restrict__ rowstart,
                                                int* __restrict__ blocksum,
                                                float* __restrict__ dinv, int n) {
    __shared__ int sh[1024];
    const int tid = threadIdx.x;
    const int i = blockIdx.x * 1024 + tid;
    int v = (i < n) ? cnt[i] : 0;
    if (i < n) dinv[i] = rsqrtf((float)(v + 1));  // +1 self-loop, always > 0
    sh[tid] = v;
    __syncthreads();
    for (int off = 1; off < 1024; off <<= 1) {
        int t = (tid >= off) ? sh[tid - off] : 0;
        __syncthreads();
        sh[tid] += t;
        __syncthreads();
    }
    if (i < n) rowstart[i] = sh[tid] - v;  // exclusive in-block
    if (tid == 1023) blocksum[blockIdx.x] = sh[1023];
}

// scan2: scans block sums in place; also zeroes pool accumulators (free ride).
__global__ __launch_bounds__(1024) void k_scan2(int* __restrict__ blocksum, int nb,
                                                float* __restrict__ psum,
                                                float* __restrict__ pcnt) {
    __shared__ int sh[1024];
    const int tid = threadIdx.x;
    int v = (tid < nb) ? blocksum[tid] : 0;
    sh[tid] = v;
    __syncthreads();
    for (int off = 1; off < 1024; off <<= 1) {
        int t = (tid >= off) ? sh[tid - off] : 0;
        __syncthreads();
        sh[tid] += t;
        __syncthreads();
    }
    if (tid < nb) blocksum[tid] = sh[tid] - v;  // exclusive
    for (int i = tid; i < NGRAPH * 32; i += 1024) psum[i] = 0.f;
    if (tid < NGRAPH) pcnt[tid] = 0.f;
}

// ---------------- merged scan3 + atomic-free scatter ----------------
__global__ __launch_bounds__(256) void k_scan3s(const int* __restrict__ src,
                                                const int* __restrict__ dst,
                                                const int* __restrict__ rank,
                                                const int* __restrict__ rowstart,
                                                const int* __restrict__ blocksum,
                                                int* __restrict__ rowfin,
                                                int* __restrict__ esrc, int n, int ne) {
    const int tid = threadIdx.x;
    const int bid = blockIdx.x;
    int i = bid * 256 + tid;
    if (i < n) rowfin[i] = rowstart[i] + blocksum[i >> 10];
    int e0 = bid * 2048 + tid;
    #pragma unroll
    for (int j = 0; j < 8; ++j) {
        int e = e0 + j * 256;
        if (e < ne) {
            int d = dst[e];
            esrc[rowstart[d] + blocksum[d >> 10] + rank[e]] = src[e];
        }
    }
}

// ---------------- MFMA GEMM: C(bf16) = dinv[row] * (act(A) @ W) ----------------
template<int COLS, bool BN, bool AF32>
__global__ __launch_bounds__(256) void k_gemm_mfma(const void* __restrict__ Av,
                                                   const ushort16* __restrict__ Wt,
                                                   const float* __restrict__ ss,
                                                   const float* __restrict__ dinv,
                                                   ushort16* __restrict__ C, int nrows) {
    constexpr int K = 128;
    constexpr int LDK = K + 8;
    __shared__ ushort16 As[64 * LDK];
    __shared__ ushort16 Bs[COLS * LDK];
    const int tid = threadIdx.x;

    {
        const uint4* wg = (const uint4*)Wt;
        for (int i = tid; i < COLS * (K / 8); i += 256) {
            int r = i >> 4, c8 = i & 15;
            *(uint4*)&Bs[r * LDK + c8 * 8] = wg[i];
        }
    }

    const int w = tid >> 6;
    const int l = tid & 63;
    const int lr = l & 15;
    const int lg = l >> 4;
    constexpr int CT = COLS / 16;

    #pragma unroll
    for (int half = 0; half < 2; ++half) {
        const int row0 = blockIdx.x * 128 + half * 64;
        if (half) __syncthreads();
        if constexpr (AF32) {
            const float* A = (const float*)Av;
            for (int i = tid; i < 64 * (K / 4); i += 256) {
                int r = i >> 5, c4 = i & 31;
                float4 a;
                if (row0 + r < nrows) a = *(const float4*)&A[(size_t)(row0 + r) * K + c4 * 4];
                else a = make_float4(0.f, 0.f, 0.f, 0.f);
                if (BN) {
                    float4 sc = *(const float4*)&ss[c4 * 4];
                    float4 sh = *(const float4*)&ss[128 + c4 * 4];
                    a.x = fmaxf(fmaf(a.x, sc.x, sh.x), 0.f);
                    a.y = fmaxf(fmaf(a.y, sc.y, sh.y), 0.f);
                    a.z = fmaxf(fmaf(a.z, sc.z, sh.z), 0.f);
                    a.w = fmaxf(fmaf(a.w, sc.w, sh.w), 0.f);
                }
                ushort4 o;
                o.x = f2bf(a.x); o.y = f2bf(a.y); o.z = f2bf(a.z); o.w = f2bf(a.w);
                *(ushort4*)&As[r * LDK + c4 * 4] = o;
            }
        } else {
            const uint4* Ag = (const uint4*)Av;
            for (int i = tid; i < 64 * (K / 8); i += 256) {
                int r = i >> 4, c8 = i & 15;
                uint4 u;
                if (row0 + r < nrows) u = Ag[(size_t)(row0 + r) * 16 + c8];
                else u = make_uint4(0, 0, 0, 0);
                if (BN) {
                    uint32 wv[4] = {u.x, u.y, u.z, u.w};
                    #pragma unroll
                    for (int t = 0; t < 4; ++t) {
                        int f = c8 * 8 + t * 2;
                        float lo = fmaxf(fmaf(bf2f(wv[t] & 0xffffu), ss[f],     ss[128 + f]),     0.f);
                        float hi = fmaxf(fmaf(bf2f(wv[t] >> 16),     ss[f + 1], ss[128 + f + 1]), 0.f);
                        wv[t] = pack2(lo, hi);
                    }
                    u.x = wv[0]; u.y = wv[1]; u.z = wv[2]; u.w = wv[3];
                }
                *(uint4*)&As[r * LDK + c8 * 8] = u;
            }
        }
        __syncthreads();

        float4v acc[CT] = {};
        short8v afrag[4];
        #pragma unroll
        for (int kk = 0; kk < 4; ++kk)
            afrag[kk] = *(const short8v*)&As[(w * 16 + lr) * LDK + kk * 32 + lg * 8];
        #pragma unroll
        for (int kk = 0; kk < 4; ++kk) {
            #pragma unroll
            for (int ct = 0; ct < CT; ++ct) {
                short8v b = *(const short8v*)&Bs[(ct * 16 + lr) * LDK + kk * 32 + lg * 8];
                acc[ct] = __builtin_amdgcn_mfma_f32_16x16x32_bf16(afrag[kk], b, acc[ct], 0, 0, 0);
            }
        }
        #pragma unroll
        for (int r = 0; r < 4; ++r) {
            int gr = row0 + w * 16 + lg * 4 + r;
            if (gr < nrows) {
                float dv = dinv[gr];
                #pragma unroll
                for (int ct = 0; ct < CT; ++ct)
                    C[(size_t)gr * COLS + ct * 16 + lr] = f2bf(acc[ct][r] * dv);
            }
        }
    }
}

// ---------------- FUSED CSR aggregation (COLS=128) + BN partial stats ----------------
// Grid-stride over node-groups (4 nodes/block/iter, 64 lanes per node). Each thread
// accumulates sum/sumsq for its 2 feature columns in registers; one LDS reduce at end.
template<bool PRESCALED>
__global__ __launch_bounds__(256) void k_agg_bn(const ushort16* __restrict__ h,
                                                const int* __restrict__ rowstart,
                                                const int* __restrict__ cnt,
                                                const int* __restrict__ esrc,
                                                const float* __restrict__ dinv,
                                                uint32* __restrict__ out,
                                                float* __restrict__ partials, int n) {
    constexpr int TPN = 64;
    const uint32* __restrict__ hu = (const uint32*)h;
    const int lane = threadIdx.x & 63;
    const int sub = threadIdx.x >> 6;
    float s0 = 0.f, s1 = 0.f, q0 = 0.f, q1 = 0.f;

    for (int node = blockIdx.x * 4 + sub; node < n; node += AGG_BLOCKS * 4) {
        float di = dinv[node];
        uint32 p = hu[(size_t)node * TPN + lane];
        float ax, ay;
        if constexpr (PRESCALED) {
            ax = bf2f(p & 0xffffu);
            ay = bf2f(p >> 16);
        } else {
            ax = bf2f(p & 0xffffu) * di;
            ay = bf2f(p >> 16) * di;
        }
        int beg = __builtin_amdgcn_readfirstlane(rowstart[node]);
        int dg  = __builtin_amdgcn_readfirstlane(cnt[node]);
        const int end = beg + dg;
        int e = beg;
        for (; e + 4 <= end; e += 4) {
            int sa = esrc[e], sb = esrc[e + 1], sc = esrc[e + 2], sd = esrc[e + 3];
            uint32 p0 = hu[(size_t)sa * TPN + lane];
            uint32 p1 = hu[(size_t)sb * TPN + lane];
            uint32 p2 = hu[(size_t)sc * TPN + lane];
            uint32 p3 = hu[(size_t)sd * TPN + lane];
            if constexpr (PRESCALED) {
                ax += bf2f(p0 & 0xffffu); ay += bf2f(p0 >> 16);
                ax += bf2f(p1 & 0xffffu); ay += bf2f(p1 >> 16);
                ax += bf2f(p2 & 0xffffu); ay += bf2f(p2 >> 16);
                ax += bf2f(p3 & 0xffffu); ay += bf2f(p3 >> 16);
            } else {
                float w0 = dinv[sa], w1 = dinv[sb], w2 = dinv[sc], w3 = dinv[sd];
                ax = fmaf(bf2f(p0 & 0xffffu), w0, ax); ay = fmaf(bf2f(p0 >> 16), w0, ay);
                ax = fmaf(bf2f(p1 & 0xffffu), w1, ax); ay = fmaf(bf2f(p1 >> 16), w1, ay);
                ax = fmaf(bf2f(p2 & 0xffffu), w2, ax); ay = fmaf(bf2f(p2 >> 16), w2, ay);
                ax = fmaf(bf2f(p3 & 0xffffu), w3, ax); ay = fmaf(bf2f(p3 >> 16), w3, ay);
            }
        }
        for (; e < end; ++e) {
            int sa = esrc[e];
            uint32 p0 = hu[(size_t)sa * TPN + lane];
            if constexpr (PRESCALED) {
                ax += bf2f(p0 & 0xffffu);
                ay += bf2f(p0 >> 16);
            } else {
                float w0 = dinv[sa];
                ax = fmaf(bf2f(p0 & 0xffffu), w0, ax);
                ay = fmaf(bf2f(p0 >> 16), w0, ay);
            }
        }
        float ox = ax * di, oy = ay * di;
        out[(size_t)node * TPN + lane] = pack2(ox, oy);
        s0 += ox; s1 += oy;
        q0 = fmaf(ox, ox, q0); q1 = fmaf(oy, oy, q1);
    }

    __shared__ float shs[4 * 128];
    __shared__ float shq[4 * 128];
    shs[sub * 128 + 2 * lane] = s0; shs[sub * 128 + 2 * lane + 1] = s1;
    shq[sub * 128 + 2 * lane] = q0; shq[sub * 128 + 2 * lane + 1] = q1;
    __syncthreads();
    int f = threadIdx.x;
    if (f < 128) {
        float s = shs[f] + shs[128 + f] + shs[256 + f] + shs[384 + f];
        float q = shq[f] + shq[128 + f] + shq[256 + f] + shq[384 + f];
        partials[(size_t)blockIdx.x * 256 + f] = s;
        partials[(size_t)blockIdx.x * 256 + 128 + f] = q;
    }
}

// ---------------- plain CSR aggregation (layer 3, COLS=32) ----------------
__global__ __launch_bounds__(256) void k_agg32(const ushort16* __restrict__ h,
                                               const int* __restrict__ rowstart,
                                               const int* __restrict__ cnt,
                                               const int* __restrict__ esrc,
                                               const float* __restrict__ dinv,
                                               uint32* __restrict__ out, int n) {
    constexpr int TPN = 16;
    const uint32* __restrict__ hu = (const uint32*)h;
    int gt = blockIdx.x * 256 + threadIdx.x;
    int node = gt / TPN;
    if (node >= n) return;
    int lane = gt % TPN;

    float di = dinv[node];
    uint32 p = hu[(size_t)node * TPN + lane];
    float ax = bf2f(p & 0xffffu);
    float ay = bf2f(p >> 16);

    const int beg = rowstart[node];
    const int end = beg + cnt[node];
    int e = beg;
    for (; e + 4 <= end; e += 4) {
        int s0 = esrc[e], s1 = esrc[e + 1], s2 = esrc[e + 2], s3 = esrc[e + 3];
        uint32 p0 = hu[(size_t)s0 * TPN + lane];
        uint32 p1 = hu[(size_t)s1 * TPN + lane];
        uint32 p2 = hu[(size_t)s2 * TPN + lane];
        uint32 p3 = hu[(size_t)s3 * TPN + lane];
        ax += bf2f(p0 & 0xffffu); ay += bf2f(p0 >> 16);
        ax += bf2f(p1 & 0xffffu); ay += bf2f(p1 >> 16);
        ax += bf2f(p2 & 0xffffu); ay += bf2f(p2 >> 16);
        ax += bf2f(p3 & 0xffffu); ay += bf2f(p3 >> 16);
    }
    for (; e < end; ++e) {
        int s0 = esrc[e];
        uint32 p0 = hu[(size_t)s0 * TPN + lane];
        ax += bf2f(p0 & 0xffffu);
        ay += bf2f(p0 >> 16);
    }
    out[(size_t)node * TPN + lane] = pack2(ax * di, ay * di);
}

// ---------------- BN stage2: reduce per-block partials, write ss directly ----------------
__global__ __launch_bounds__(256) void k_bn_stats2(const float* __restrict__ partials,
                                                   const float* __restrict__ gamma,
                                                   const float* __restrict__ beta,
                                                   float* __restrict__ ss, int n) {
    const int f16 = threadIdx.x & 15;
    const int rl = threadIdx.x >> 4;   // 0..15
    const int f = blockIdx.x * 16 + f16;
    float s = 0.f, q = 0.f;
    for (int r = rl; r < AGG_BLOCKS; r += 16) {
        s += partials[(size_t)r * 256 + f];
        q += partials[(size_t)r * 256 + 128 + f];
    }
    __shared__ float shs[256], shq[256];
    shs[threadIdx.x] = s;
    shq[threadIdx.x] = q;
    __syncthreads();
    if (rl == 0) {
        float S = 0.f, Q = 0.f;
        #pragma unroll
        for (int r = 0; r < 16; ++r) { S += shs[r * 16 + f16]; Q += shq[r * 16 + f16]; }
        float inv_n = 1.0f / (float)n;
        float mean = S * inv_n;
        float var = Q * inv_n - mean * mean;
        float scale = gamma[f] * rsqrtf(var + EPS_BN);
        ss[f] = scale;
        ss[128 + f] = beta[f] - mean * scale;
    }
}

// ---------------- pool: sorted-batch run-length private accumulation (bf16 in) ----------------
#define POOL_SLICE 32
__global__ __launch_bounds__(256) void k_pool2(const uint32* __restrict__ h3,
                                               const int* __restrict__ batch,
                                               float* __restrict__ sums,
                                               float* __restrict__ cnt, int n) {
    const int fp = threadIdx.x & 15;
    const int sub = threadIdx.x >> 4;
    int node0 = blockIdx.x * (16 * POOL_SLICE) + sub * POOL_SLICE;
    if (node0 >= n) return;
    int node1 = min(node0 + POOL_SLICE, n);

    int cur_g = batch[node0];
    float a0 = 0.f, a1 = 0.f, c = 0.f;
    for (int i = node0; i < node1; ++i) {
        int g = batch[i];
        if (g != cur_g) {
            atomicAdd(&sums[cur_g * 32 + 2 * fp], a0);
            atomicAdd(&sums[cur_g * 32 + 2 * fp + 1], a1);
            if (fp == 0) atomicAdd(&cnt[cur_g], c);
            a0 = 0.f; a1 = 0.f; c = 0.f; cur_g = g;
        }
        uint32 u = h3[(size_t)i * 16 + fp];
        a0 += bf2f(u & 0xffffu);
        a1 += bf2f(u >> 16);
        c += 1.f;
    }
    atomicAdd(&sums[cur_g * 32 + 2 * fp], a0);
    atomicAdd(&sums[cur_g * 32 + 2 * fp + 1], a1);
    if (fp == 0) atomicAdd(&cnt[cur_g], c);
}

__global__ __launch_bounds__(256) void k_final(const float* __restrict__ sums,
                                               const float* __restrict__ cnt,
                                               const float* __restrict__ b3,
                                               float* __restrict__ out) {
    int i = blockIdx.x * 256 + threadIdx.x;
    if (i >= NGRAPH * 32) return;
    int g = i >> 5;
    int f = i & 31;
    float c = fmaxf(cnt[g], 1.0f);
    float v = sums[i] / c + b3[f];
    out[i] = 1.0f / (1.0f + expf(-v));
}

// ---------------- launch ----------------
extern "C" void kernel_launch(void* const* d_in, const int* in_sizes, int n_in,
                              void* d_out, int out_size, void* d_ws, size_t ws_size,
                              hipStream_t stream) {
    const float* x      = (const float*)d_in[0];
    const int*   eidx   = (const int*)d_in[1];
    const int*   batch  = (const int*)d_in[2];
    const float* W1     = (const float*)d_in[3];
    const float* W2     = (const float*)d_in[5];
    const float* W3     = (const float*)d_in[7];
    const float* b3     = (const float*)d_in[8];
    const float* gamma1 = (const float*)d_in[9];
    const float* beta1  = (const float*)d_in[10];
    const float* gamma2 = (const float*)d_in[11];
    const float* beta2  = (const float*)d_in[12];

    const int N = in_sizes[0] / 128;
    const int E = in_sizes[1] / 2;
    const int* src = eidx;
    const int* dst = eidx + E;

    size_t off = 0;
    auto carve = [&](size_t bytes) {
        char* p = (char*)d_ws + off;
        off += (bytes + 511) & ~(size_t)511;
        return p;
    };
    const size_t NB = (size_t)N * 128 * sizeof(float);
    ushort16* bufA  = (ushort16*)carve(NB / 2);     // bf16 h (gather source)
    uint32* bufB    = (uint32*)carve(NB / 2);       // bf16 agg output (packed)
    int*   cnt      = (int*)carve((size_t)N * 4);
    int*   rowstart = (int*)carve((size_t)N * 4);   // raw (pre-offset)
    int*   rowfin   = (int*)carve((size_t)N * 4);   // final row starts
    float* dinv     = (float*)carve((size_t)N * 4);
    int*   esrc     = (int*)carve((size_t)E * 4);
    int*   rank     = (int*)carve((size_t)E * 4);
    ushort16* wt1   = (ushort16*)carve(128 * 128 * 2);
    ushort16* wt2   = (ushort16*)carve(128 * 128 * 2);
    ushort16* wt3   = (ushort16*)carve(32 * 128 * 2);
    float* ss1      = (float*)carve(256 * 4);
    float* ss2      = (float*)carve(256 * 4);
    float* partials = (float*)carve((size_t)AGG_BLOCKS * 256 * 4);
    int*   blocksum = (int*)carve(1024 * 4);
    float* psum     = (float*)carve(NGRAPH * 32 * 4);
    float* pcnt     = (float*)carve(NGRAPH * 4);
    (void)ws_size; (void)n_in; (void)out_size;

    const int nbScan  = (N + 1023) / 1024;
    const int nbGemm  = (N + 127) / 128;
    const int nblkAgg32  = ((size_t)N * 16 + 255) / 256;
    const int nblkPool   = (N + 16 * POOL_SLICE - 1) / (16 * POOL_SLICE);
    const int nbWprep    = (((36864 > N) ? 36864 : N) + 255) / 256;
    const int nbS3       = (E + 2047) / 2048;
    const int epb        = (E + EB - 1) / EB;
    const int nbFused    = nbGemm + EB;             // requires nbGemm >= 3*EB (N=100k: 782>=768)

    // --- W prep (bf16, transposed) + cnt zeroing ---
    k_wprep_all<<<nbWprep, 256, 0, stream>>>(W1, W2, W3, wt1, wt2, wt3, cnt, N);

    // --- FUSED layer-1 GEMM (unscaled h) + edge histogram/rank ---
    k_gemm1_cnt<<<nbFused, 256, 0, stream>>>(x, wt1, bufA, N, dst, cnt, rank, E, epb);

    // --- scan + scatter ---
    k_scan1<<<nbScan, 1024, 0, stream>>>(cnt, rowstart, blocksum, dinv, N);
    k_scan2<<<1, 1024, 0, stream>>>(blocksum, nbScan, psum, pcnt);
    k_scan3s<<<nbS3, 256, 0, stream>>>(src, dst, rank, rowstart, blocksum, rowfin, esrc, N, E);

    // --- layer 1 agg (+BN stats fused) ---
    k_agg_bn<false><<<AGG_BLOCKS, 256, 0, stream>>>(bufA, rowfin, cnt, esrc, dinv, bufB, partials, N);
    k_bn_stats2<<<8, 256, 0, stream>>>(partials, gamma1, beta1, ss1, N);

    // --- layer 2 (BN1+ReLU fused into A-staging) + agg (+BN stats fused) ---
    k_gemm_mfma<128, true, false><<<nbGemm, 256, 0, stream>>>(bufB, wt2, ss1, dinv, bufA, N);
    k_agg_bn<true><<<AGG_BLOCKS, 256, 0, stream>>>(bufA, rowfin, cnt, esrc, dinv, bufB, partials, N);
    k_bn_stats2<<<8, 256, 0, stream>>>(partials, gamma2, beta2, ss2, N);

    // --- layer 3 (128 -> 32, BN2+ReLU fused) ---
    k_gemm_mfma<32, true, false><<<nbGemm, 256, 0, stream>>>(bufB, wt3, ss2, dinv, bufA, N);
    k_agg32<<<nblkAgg32, 256, 0, stream>>>(bufA, rowfin, cnt, esrc, dinv, bufB, N);

    // --- pool + sigmoid (b3 added post-pool; psum/pcnt zeroed in scan2) ---
    k_pool2<<<nblkPool, 256, 0, stream>>>(bufB, batch, psum, pcnt, N);
    k_final<<<(NGRAPH * 32 + 255) / 256, 256, 0, stream>>>(psum, pcnt, b3, (float*)d_out);
}

// Round 14
// 396.465 us; speedup vs baseline: 1.0463x; 1.0463x over previous
//
#include <hip/hip_runtime.h>
#include <math.h>

#define NGRAPH 64
#define EPS_BN 1e-5f
#define BN_BLOCKS 512

typedef unsigned int uint32;
typedef unsigned short ushort16;
typedef __attribute__((ext_vector_type(8))) short short8v;
typedef __attribute__((ext_vector_type(4))) float float4v;

__device__ __forceinline__ float bf2f(uint32 u16) {
    return __uint_as_float(u16 << 16);
}
__device__ __forceinline__ ushort16 f2bf(float f) {
    uint32 u = __float_as_uint(f);
    return (ushort16)((u + 0x7fffu + ((u >> 16) & 1u)) >> 16);  // RNE
}
__device__ __forceinline__ uint32 pack2(float lo, float hi) {
    return (uint32)f2bf(lo) | ((uint32)f2bf(hi) << 16);
}

// ---------------- merged W prep + cnt zeroing + pool-accumulator zeroing ----------------
__global__ __launch_bounds__(256) void k_wprep_all(const float* __restrict__ W1,
                                                   const float* __restrict__ W2,
                                                   const float* __restrict__ W3,
                                                   ushort16* __restrict__ wt1,
                                                   ushort16* __restrict__ wt2,
                                                   ushort16* __restrict__ wt3,
                                                   int* __restrict__ cnt,
                                                   float* __restrict__ psum,
                                                   float* __restrict__ pcnt, int n) {
    int i = blockIdx.x * 256 + threadIdx.x;
    if (i < 16384) {
        int c = i >> 7, k = i & 127;
        wt1[i] = f2bf(W1[k * 128 + c]);
    } else if (i < 32768) {
        int j = i - 16384;
        int c = j >> 7, k = j & 127;
        wt2[j] = f2bf(W2[k * 128 + c]);
    } else if (i < 36864) {
        int j = i - 32768;
        int c = j >> 7, k = j & 127;  // c in [0,32)
        wt3[j] = f2bf(W3[k * 32 + c]);
    } else if (i < 36864 + NGRAPH * 32) {
        psum[i - 36864] = 0.f;
    } else if (i < 36864 + NGRAPH * 32 + NGRAPH) {
        pcnt[i - 36864 - NGRAPH * 32] = 0.f;
    }
    if (i < n) cnt[i] = 0;
}

// ---------------- FUSED: layer-1 GEMM (no BN, no dinv scale) + edge histogram+rank ----------------
#define EB 256
__global__ __launch_bounds__(256) void k_gemm1_cnt(const float* __restrict__ A,
                                                   const ushort16* __restrict__ Wt,
                                                   ushort16* __restrict__ C, int nrows,
                                                   const int* __restrict__ dst,
                                                   int* __restrict__ cnt,
                                                   int* __restrict__ rank,
                                                   int ne, int epb) {
    constexpr int K = 128;
    constexpr int COLS = 128;
    constexpr int LDK = K + 8;
    __shared__ ushort16 As[64 * LDK];
    __shared__ ushort16 Bs[COLS * LDK];
    const int tid = threadIdx.x;
    const int bid = blockIdx.x;
    const int q = bid >> 2, r = bid & 3;

    if (r == 3 && q < EB) {
        const int beg = q * epb;
        const int end = min(beg + epb, ne);
        int e = beg + tid;
        for (; e + 3 * 256 < end; e += 4 * 256) {
            int d0 = dst[e], d1 = dst[e + 256], d2 = dst[e + 512], d3 = dst[e + 768];
            int r0 = atomicAdd(&cnt[d0], 1);
            int r1 = atomicAdd(&cnt[d1], 1);
            int r2 = atomicAdd(&cnt[d2], 1);
            int r3 = atomicAdd(&cnt[d3], 1);
            rank[e] = r0; rank[e + 256] = r1; rank[e + 512] = r2; rank[e + 768] = r3;
        }
        for (; e < end; e += 256) rank[e] = atomicAdd(&cnt[dst[e]], 1);
        return;
    }
    const int gidx = (q < EB) ? (3 * q + r) : (bid - EB);

    {
        const uint4* wg = (const uint4*)Wt;
        for (int i = tid; i < COLS * (K / 8); i += 256) {
            int rr = i >> 4, c8 = i & 15;
            *(uint4*)&Bs[rr * LDK + c8 * 8] = wg[i];
        }
    }
    const int w = tid >> 6;
    const int l = tid & 63;
    const int lr = l & 15;
    const int lg = l >> 4;
    constexpr int CT = COLS / 16;

    #pragma unroll
    for (int half = 0; half < 2; ++half) {
        const int row0 = gidx * 128 + half * 64;
        if (half) __syncthreads();
        const float* Af = A;
        for (int i = tid; i < 64 * (K / 4); i += 256) {
            int rr = i >> 5, c4 = i & 31;
            float4 a;
            if (row0 + rr < nrows) a = *(const float4*)&Af[(size_t)(row0 + rr) * K + c4 * 4];
            else a = make_float4(0.f, 0.f, 0.f, 0.f);
            ushort4 o;
            o.x = f2bf(a.x); o.y = f2bf(a.y); o.z = f2bf(a.z); o.w = f2bf(a.w);
            *(ushort4*)&As[rr * LDK + c4 * 4] = o;
        }
        __syncthreads();

        float4v acc[CT] = {};
        short8v afrag[4];
        #pragma unroll
        for (int kk = 0; kk < 4; ++kk)
            afrag[kk] = *(const short8v*)&As[(w * 16 + lr) * LDK + kk * 32 + lg * 8];
        #pragma unroll
        for (int kk = 0; kk < 4; ++kk) {
            #pragma unroll
            for (int ct = 0; ct < CT; ++ct) {
                short8v b = *(const short8v*)&Bs[(ct * 16 + lr) * LDK + kk * 32 + lg * 8];
                acc[ct] = __builtin_amdgcn_mfma_f32_16x16x32_bf16(afrag[kk], b, acc[ct], 0, 0, 0);
            }
        }
        #pragma unroll
        for (int rr = 0; rr < 4; ++rr) {
            int gr = row0 + w * 16 + lg * 4 + rr;
            if (gr < nrows) {
                #pragma unroll
                for (int ct = 0; ct < CT; ++ct)
                    C[(size_t)gr * COLS + ct * 16 + lr] = f2bf(acc[ct][rr]);
            }
        }
    }
}

// ---------------- hierarchical exclusive scan, stage 1 ----------------
__global__ __launch_bounds__(1024) void k_scan1(const int* __restrict__ cnt,
                                                int* __restrict__ rowstart,
                                                int* __restrict__ blocksum,
                                                float* __restrict__ dinv, int n) {
    __shared__ int sh[1024];
    const int tid = threadIdx.x;
    const int i = blockIdx.x * 1024 + tid;
    int v = (i < n) ? cnt[i] : 0;
    if (i < n) dinv[i] = rsqrtf((float)(v + 1));  // +1 self-loop, always > 0
    sh[tid] = v;
    __syncthreads();
    for (int off = 1; off < 1024; off <<= 1) {
        int t = (tid >= off) ? sh[tid - off] : 0;
        __syncthreads();
        sh[tid] += t;
        __syncthreads();
    }
    if (i < n) rowstart[i] = sh[tid] - v;  // exclusive in-block
    if (tid == 1023) blocksum[blockIdx.x] = sh[1023];
}

// ---------------- merged {scan2 inline} + scan3 + atomic-free scatter ----------------
// Each block redundantly scans the <=128 raw blocksums in LDS (cheap), then:
//   rowfin[i] = rowstart_raw[i] + excl[i>>10]
//   esrc[rowstart_raw[d] + excl[d>>10] + rank[e]] = src[e]
__global__ __launch_bounds__(256) void k_scan3s(const int* __restrict__ src,
                                                const int* __restrict__ dst,
                                                const int* __restrict__ rank,
                                                const int* __restrict__ rowstart,
                                                const int* __restrict__ blocksum,
                                                int* __restrict__ rowfin,
                                                int* __restrict__ esrc,
                                                int n, int ne, int nb) {
    __shared__ int incl[128];
    __shared__ int exc[128];
    const int tid = threadIdx.x;
    int v = 0;
    if (tid < 128) {
        v = (tid < nb) ? blocksum[tid] : 0;
        incl[tid] = v;
    }
    __syncthreads();
    #pragma unroll
    for (int d = 1; d < 128; d <<= 1) {
        int t = (tid < 128 && tid >= d) ? incl[tid - d] : 0;
        __syncthreads();
        if (tid < 128) incl[tid] += t;
        __syncthreads();
    }
    if (tid < 128) exc[tid] = incl[tid] - v;
    __syncthreads();

    const int bid = blockIdx.x;
    int i = bid * 256 + tid;
    if (i < n) rowfin[i] = rowstart[i] + exc[i >> 10];
    int e0 = bid * 2048 + tid;
    #pragma unroll
    for (int j = 0; j < 8; ++j) {
        int e = e0 + j * 256;
        if (e < ne) {
            int d = dst[e];
            esrc[rowstart[d] + exc[d >> 10] + rank[e]] = src[e];
        }
    }
}

// ---------------- MFMA GEMM: C(bf16) = dinv[row] * (act(A) @ W) ----------------
template<int COLS, bool BN, bool AF32>
__global__ __launch_bounds__(256) void k_gemm_mfma(const void* __restrict__ Av,
                                                   const ushort16* __restrict__ Wt,
                                                   const float* __restrict__ ss,
                                                   const float* __restrict__ dinv,
                                                   ushort16* __restrict__ C, int nrows) {
    constexpr int K = 128;
    constexpr int LDK = K + 8;
    __shared__ ushort16 As[64 * LDK];
    __shared__ ushort16 Bs[COLS * LDK];
    const int tid = threadIdx.x;

    {
        const uint4* wg = (const uint4*)Wt;
        for (int i = tid; i < COLS * (K / 8); i += 256) {
            int r = i >> 4, c8 = i & 15;
            *(uint4*)&Bs[r * LDK + c8 * 8] = wg[i];
        }
    }

    const int w = tid >> 6;
    const int l = tid & 63;
    const int lr = l & 15;
    const int lg = l >> 4;
    constexpr int CT = COLS / 16;

    #pragma unroll
    for (int half = 0; half < 2; ++half) {
        const int row0 = blockIdx.x * 128 + half * 64;
        if (half) __syncthreads();
        if constexpr (AF32) {
            const float* A = (const float*)Av;
            for (int i = tid; i < 64 * (K / 4); i += 256) {
                int r = i >> 5, c4 = i & 31;
                float4 a;
                if (row0 + r < nrows) a = *(const float4*)&A[(size_t)(row0 + r) * K + c4 * 4];
                else a = make_float4(0.f, 0.f, 0.f, 0.f);
                if (BN) {
                    float4 sc = *(const float4*)&ss[c4 * 4];
                    float4 sh = *(const float4*)&ss[128 + c4 * 4];
                    a.x = fmaxf(fmaf(a.x, sc.x, sh.x), 0.f);
                    a.y = fmaxf(fmaf(a.y, sc.y, sh.y), 0.f);
                    a.z = fmaxf(fmaf(a.z, sc.z, sh.z), 0.f);
                    a.w = fmaxf(fmaf(a.w, sc.w, sh.w), 0.f);
                }
                ushort4 o;
                o.x = f2bf(a.x); o.y = f2bf(a.y); o.z = f2bf(a.z); o.w = f2bf(a.w);
                *(ushort4*)&As[r * LDK + c4 * 4] = o;
            }
        } else {
            const uint4* Ag = (const uint4*)Av;
            for (int i = tid; i < 64 * (K / 8); i += 256) {
                int r = i >> 4, c8 = i & 15;
                uint4 u;
                if (row0 + r < nrows) u = Ag[(size_t)(row0 + r) * 16 + c8];
                else u = make_uint4(0, 0, 0, 0);
                if (BN) {
                    uint32 wv[4] = {u.x, u.y, u.z, u.w};
                    #pragma unroll
                    for (int t = 0; t < 4; ++t) {
                        int f = c8 * 8 + t * 2;
                        float lo = fmaxf(fmaf(bf2f(wv[t] & 0xffffu), ss[f],     ss[128 + f]),     0.f);
                        float hi = fmaxf(fmaf(bf2f(wv[t] >> 16),     ss[f + 1], ss[128 + f + 1]), 0.f);
                        wv[t] = pack2(lo, hi);
                    }
                    u.x = wv[0]; u.y = wv[1]; u.z = wv[2]; u.w = wv[3];
                }
                *(uint4*)&As[r * LDK + c8 * 8] = u;
            }
        }
        __syncthreads();

        float4v acc[CT] = {};
        short8v afrag[4];
        #pragma unroll
        for (int kk = 0; kk < 4; ++kk)
            afrag[kk] = *(const short8v*)&As[(w * 16 + lr) * LDK + kk * 32 + lg * 8];
        #pragma unroll
        for (int kk = 0; kk < 4; ++kk) {
            #pragma unroll
            for (int ct = 0; ct < CT; ++ct) {
                short8v b = *(const short8v*)&Bs[(ct * 16 + lr) * LDK + kk * 32 + lg * 8];
                acc[ct] = __builtin_amdgcn_mfma_f32_16x16x32_bf16(afrag[kk], b, acc[ct], 0, 0, 0);
            }
        }
        #pragma unroll
        for (int r = 0; r < 4; ++r) {
            int gr = row0 + w * 16 + lg * 4 + r;
            if (gr < nrows) {
                float dv = dinv[gr];
                #pragma unroll
                for (int ct = 0; ct < CT; ++ct)
                    C[(size_t)gr * COLS + ct * 16 + lr] = f2bf(acc[ct][r] * dv);
            }
        }
    }
}

// ---------------- CSR aggregation (R8/R12-proven form) ----------------
// PRESCALED: h already scaled by dinv[row] -> out = dinv[n]*(h'[n] + sum h'[s]).
// else (layer 1): out = dinv[n]*(dinv[n]*h[n] + sum dinv[s]*h[s]).
template<int COLS, bool PRESCALED>
__global__ __launch_bounds__(256) void k_agg_csr(const ushort16* __restrict__ h,
                                                 const int* __restrict__ rowstart,
                                                 const int* __restrict__ cnt,
                                                 const int* __restrict__ esrc,
                                                 const float* __restrict__ dinv,
                                                 uint32* __restrict__ out, int n) {
    constexpr int TPN = COLS / 2;
    const uint32* __restrict__ hu = (const uint32*)h;
    int gt = blockIdx.x * 256 + threadIdx.x;
    int node = gt / TPN;
    if (node >= n) return;
    int lane = gt % TPN;

    float di = dinv[node];
    uint32 p = hu[(size_t)node * TPN + lane];
    float ax, ay;
    if constexpr (PRESCALED) {
        ax = bf2f(p & 0xffffu);
        ay = bf2f(p >> 16);
    } else {
        ax = bf2f(p & 0xffffu) * di;
        ay = bf2f(p >> 16) * di;
    }

    int beg = rowstart[node];
    int dg = cnt[node];
    if constexpr (TPN == 64) {
        beg = __builtin_amdgcn_readfirstlane(beg);
        dg = __builtin_amdgcn_readfirstlane(dg);
    }
    const int end = beg + dg;
    int e = beg;
    for (; e + 4 <= end; e += 4) {
        int s0 = esrc[e], s1 = esrc[e + 1], s2 = esrc[e + 2], s3 = esrc[e + 3];
        uint32 p0 = hu[(size_t)s0 * TPN + lane];
        uint32 p1 = hu[(size_t)s1 * TPN + lane];
        uint32 p2 = hu[(size_t)s2 * TPN + lane];
        uint32 p3 = hu[(size_t)s3 * TPN + lane];
        if constexpr (PRESCALED) {
            ax += bf2f(p0 & 0xffffu); ay += bf2f(p0 >> 16);
            ax += bf2f(p1 & 0xffffu); ay += bf2f(p1 >> 16);
            ax += bf2f(p2 & 0xffffu); ay += bf2f(p2 >> 16);
            ax += bf2f(p3 & 0xffffu); ay += bf2f(p3 >> 16);
        } else {
            float w0 = dinv[s0], w1 = dinv[s1], w2 = dinv[s2], w3 = dinv[s3];
            ax = fmaf(bf2f(p0 & 0xffffu), w0, ax); ay = fmaf(bf2f(p0 >> 16), w0, ay);
            ax = fmaf(bf2f(p1 & 0xffffu), w1, ax); ay = fmaf(bf2f(p1 >> 16), w1, ay);
            ax = fmaf(bf2f(p2 & 0xffffu), w2, ax); ay = fmaf(bf2f(p2 >> 16), w2, ay);
            ax = fmaf(bf2f(p3 & 0xffffu), w3, ax); ay = fmaf(bf2f(p3 >> 16), w3, ay);
        }
    }
    for (; e < end; ++e) {
        int s0 = esrc[e];
        uint32 p0 = hu[(size_t)s0 * TPN + lane];
        if constexpr (PRESCALED) {
            ax += bf2f(p0 & 0xffffu);
            ay += bf2f(p0 >> 16);
        } else {
            float w0 = dinv[s0];
            ax = fmaf(bf2f(p0 & 0xffffu), w0, ax);
            ay = fmaf(bf2f(p0 >> 16), w0, ay);
        }
    }
    out[(size_t)node * TPN + lane] = pack2(ax * di, ay * di);
}

// ---------------- BatchNorm stats: 2-stage reduction over packed-bf16 x ----------------
__global__ __launch_bounds__(256) void k_bn_stats1(const uint32* __restrict__ x,
                                                   float* __restrict__ partials, int n) {
    const int cp = threadIdx.x & 63;
    const int rl = threadIdx.x >> 6;
    float s0 = 0.f, s1 = 0.f, q0 = 0.f, q1 = 0.f;
    for (int r = blockIdx.x * 4 + rl; r < n; r += BN_BLOCKS * 4) {
        uint32 u = x[(size_t)r * 64 + cp];
        float lo = bf2f(u & 0xffffu), hi = bf2f(u >> 16);
        s0 += lo; s1 += hi;
        q0 = fmaf(lo, lo, q0); q1 = fmaf(hi, hi, q1);
    }
    __shared__ float shs[4 * 128];
    __shared__ float shq[4 * 128];
    shs[rl * 128 + 2 * cp] = s0; shs[rl * 128 + 2 * cp + 1] = s1;
    shq[rl * 128 + 2 * cp] = q0; shq[rl * 128 + 2 * cp + 1] = q1;
    __syncthreads();
    int f = threadIdx.x;
    if (f < 128) {
        float s = shs[f] + shs[128 + f] + shs[256 + f] + shs[384 + f];
        float q = shq[f] + shq[128 + f] + shq[256 + f] + shq[384 + f];
        partials[(size_t)blockIdx.x * 256 + f] = s;
        partials[(size_t)blockIdx.x * 256 + 128 + f] = q;
    }
}

// stage2: 8 blocks x 16 feats each; reduces partials and writes ss directly.
__global__ __launch_bounds__(256) void k_bn_stats2(const float* __restrict__ partials,
                                                   const float* __restrict__ gamma,
                                                   const float* __restrict__ beta,
                                                   float* __restrict__ ss, int n) {
    const int f16 = threadIdx.x & 15;
    const int rl = threadIdx.x >> 4;
    const int f = blockIdx.x * 16 + f16;
    float s = 0.f, q = 0.f;
    for (int r = rl; r < BN_BLOCKS; r += 16) {
        s += partials[(size_t)r * 256 + f];
        q += partials[(size_t)r * 256 + 128 + f];
    }
    __shared__ float shs[256], shq[256];
    shs[threadIdx.x] = s;
    shq[threadIdx.x] = q;
    __syncthreads();
    if (rl == 0) {
        float S = 0.f, Q = 0.f;
        #pragma unroll
        for (int r = 0; r < 16; ++r) { S += shs[r * 16 + f16]; Q += shq[r * 16 + f16]; }
        float inv_n = 1.0f / (float)n;
        float mean = S * inv_n;
        float var = Q * inv_n - mean * mean;
        float scale = gamma[f] * rsqrtf(var + EPS_BN);
        ss[f] = scale;
        ss[128 + f] = beta[f] - mean * scale;
    }
}

// ---------------- pool: sorted-batch run-length private accumulation (bf16 in) ----------------
#define POOL_SLICE 128
__global__ __launch_bounds__(256) void k_pool2(const uint32* __restrict__ h3,
                                               const int* __restrict__ batch,
                                               float* __restrict__ sums,
                                               float* __restrict__ cnt, int n) {
    const int fp = threadIdx.x & 15;
    const int sub = threadIdx.x >> 4;
    int node0 = blockIdx.x * (16 * POOL_SLICE) + sub * POOL_SLICE;
    if (node0 >= n) return;
    int node1 = min(node0 + POOL_SLICE, n);

    int cur_g = batch[node0];
    float a0 = 0.f, a1 = 0.f, c = 0.f;
    for (int i = node0; i < node1; ++i) {
        int g = batch[i];
        if (g != cur_g) {
            atomicAdd(&sums[cur_g * 32 + 2 * fp], a0);
            atomicAdd(&sums[cur_g * 32 + 2 * fp + 1], a1);
            if (fp == 0) atomicAdd(&cnt[cur_g], c);
            a0 = 0.f; a1 = 0.f; c = 0.f; cur_g = g;
        }
        uint32 u = h3[(size_t)i * 16 + fp];
        a0 += bf2f(u & 0xffffu);
        a1 += bf2f(u >> 16);
        c += 1.f;
    }
    atomicAdd(&sums[cur_g * 32 + 2 * fp], a0);
    atomicAdd(&sums[cur_g * 32 + 2 * fp + 1], a1);
    if (fp == 0) atomicAdd(&cnt[cur_g], c);
}

__global__ __launch_bounds__(256) void k_final(const float* __restrict__ sums,
                                               const float* __restrict__ cnt,
                                               const float* __restrict__ b3,
                                               float* __restrict__ out) {
    int i = blockIdx.x * 256 + threadIdx.x;
    if (i >= NGRAPH * 32) return;
    int g = i >> 5;
    int f = i & 31;
    float c = fmaxf(cnt[g], 1.0f);
    float v = sums[i] / c + b3[f];
    out[i] = 1.0f / (1.0f + expf(-v));
}

// ---------------- launch ----------------
extern "C" void kernel_launch(void* const* d_in, const int* in_sizes, int n_in,
                              void* d_out, int out_size, void* d_ws, size_t ws_size,
                              hipStream_t stream) {
    const float* x      = (const float*)d_in[0];
    const int*   eidx   = (const int*)d_in[1];
    const int*   batch  = (const int*)d_in[2];
    const float* W1     = (const float*)d_in[3];
    const float* W2     = (const float*)d_in[5];
    const float* W3     = (const float*)d_in[7];
    const float* b3     = (const float*)d_in[8];
    const float* gamma1 = (const float*)d_in[9];
    const float* beta1  = (const float*)d_in[10];
    const float* gamma2 = (const float*)d_in[11];
    const float* beta2  = (const float*)d_in[12];

    const int N = in_sizes[0] / 128;
    const int E = in_sizes[1] / 2;
    const int* src = eidx;
    const int* dst = eidx + E;

    size_t off = 0;
    auto carve = [&](size_t bytes) {
        char* p = (char*)d_ws + off;
        off += (bytes + 511) & ~(size_t)511;
        return p;
    };
    const size_t NB = (size_t)N * 128 * sizeof(float);
    ushort16* bufA  = (ushort16*)carve(NB / 2);     // bf16 h (gather source)
    uint32* bufB    = (uint32*)carve(NB / 2);       // bf16 agg output (packed)
    int*   cnt      = (int*)carve((size_t)N * 4);
    int*   rowstart = (int*)carve((size_t)N * 4);   // raw (pre-offset)
    int*   rowfin   = (int*)carve((size_t)N * 4);   // final row starts
    float* dinv     = (float*)carve((size_t)N * 4);
    int*   esrc     = (int*)carve((size_t)E * 4);
    int*   rank     = (int*)carve((size_t)E * 4);
    ushort16* wt1   = (ushort16*)carve(128 * 128 * 2);
    ushort16* wt2   = (ushort16*)carve(128 * 128 * 2);
    ushort16* wt3   = (ushort16*)carve(32 * 128 * 2);
    float* ss1      = (float*)carve(256 * 4);
    float* ss2      = (float*)carve(256 * 4);
    float* partials = (float*)carve((size_t)BN_BLOCKS * 256 * 4);
    int*   blocksum = (int*)carve(1024 * 4);
    float* psum     = (float*)carve(NGRAPH * 32 * 4);
    float* pcnt     = (float*)carve(NGRAPH * 4);
    (void)ws_size; (void)n_in; (void)out_size;

    const int nbScan  = (N + 1023) / 1024;          // <=128 required by scan3s inline scan
    const int nbGemm  = (N + 127) / 128;
    const int nblkAgg128 = ((size_t)N * 64 + 255) / 256;
    const int nblkAgg32  = ((size_t)N * 16 + 255) / 256;
    const int nblkPool   = (N + 16 * POOL_SLICE - 1) / (16 * POOL_SLICE);
    const int nbWprepMin = 36864 + NGRAPH * 32 + NGRAPH;
    const int nbWprep    = (((nbWprepMin > N) ? nbWprepMin : N) + 255) / 256;
    const int nbS3       = (E + 2047) / 2048;       // also covers N (N <= nbS3*256)
    const int epb        = (E + EB - 1) / EB;
    const int nbFused    = nbGemm + EB;             // requires nbGemm >= 3*EB (N=100k: 782>=768)

    // --- W prep (bf16, transposed) + cnt/psum/pcnt zeroing ---
    k_wprep_all<<<nbWprep, 256, 0, stream>>>(W1, W2, W3, wt1, wt2, wt3, cnt, psum, pcnt, N);

    // --- FUSED layer-1 GEMM (unscaled h) + edge histogram/rank ---
    k_gemm1_cnt<<<nbFused, 256, 0, stream>>>(x, wt1, bufA, N, dst, cnt, rank, E, epb);

    // --- scan + scatter (scan2 inlined into scan3s) ---
    k_scan1<<<nbScan, 1024, 0, stream>>>(cnt, rowstart, blocksum, dinv, N);
    k_scan3s<<<nbS3, 256, 0, stream>>>(src, dst, rank, rowstart, blocksum, rowfin, esrc, N, E, nbScan);

    // --- layer 1 agg (h unscaled -> per-edge dinv) + BN ---
    k_agg_csr<128, false><<<nblkAgg128, 256, 0, stream>>>(bufA, rowfin, cnt, esrc, dinv, bufB, N);
    k_bn_stats1<<<BN_BLOCKS, 256, 0, stream>>>(bufB, partials, N);
    k_bn_stats2<<<8, 256, 0, stream>>>(partials, gamma1, beta1, ss1, N);

    // --- layer 2 (BN1+ReLU fused into A-staging, bf16 A, dinv-prescaled h) ---
    k_gemm_mfma<128, true, false><<<nbGemm, 256, 0, stream>>>(bufB, wt2, ss1, dinv, bufA, N);
    k_agg_csr<128, true><<<nblkAgg128, 256, 0, stream>>>(bufA, rowfin, cnt, esrc, dinv, bufB, N);
    k_bn_stats1<<<BN_BLOCKS, 256, 0, stream>>>(bufB, partials, N);
    k_bn_stats2<<<8, 256, 0, stream>>>(partials, gamma2, beta2, ss2, N);

    // --- layer 3 (128 -> 32, BN2+ReLU fused, bf16 A, dinv-prescaled h) ---
    k_gemm_mfma<32, true, false><<<nbGemm, 256, 0, stream>>>(bufB, wt3, ss2, dinv, bufA, N);
    k_agg_csr<32, true><<<nblkAgg32, 256, 0, stream>>>(bufA, rowfin, cnt, esrc, dinv, bufB, N);

    // --- pool + sigmoid (b3 added post-pool; psum/pcnt zeroed in wprep) ---
    k_pool2<<<nblkPool, 256, 0, stream>>>(bufB, batch, psum, pcnt, N);
    k_final<<<(NGRAPH * 32 + 255) / 256, 256, 0, stream>>>(psum, pcnt, b3, (float*)d_out);
}